// Round 2
// baseline (1696.908 us; speedup 1.0000x reference)
//
#include <hip/hip_runtime.h>
#include <hip/hip_bf16.h>

#define B_ 2
#define N_ 8
#define C_ 64
#define H_ 192
#define W_ 256
#define V_ 200000
#define OUT_ 128
#define HW_ (H_*W_)        // 49152
#define R_ (N_*HW_)        // 393216

// ---------------- Kernel 1: ray directions ----------------
// d[b,n,h,w,i] = normalize(p[i][0]*uu + p[i][1]*vv + p[i][2])
__global__ __launch_bounds__(256) void ray_kernel(
    const float* __restrict__ pose,
    const float* __restrict__ intr,
    float* __restrict__ dout)
{
    const int blocksPerBN = HW_ / 256;  // 192
    int tid = threadIdx.x;
    int bn = blockIdx.x / blocksPerBN;
    int hw = (blockIdx.x % blocksPerBN) * 256 + tid;
    int h = hw / W_, w = hw % W_;

    __shared__ float p[12];
    __shared__ float it[4];
    if (tid < 12) p[tid] = pose[bn * 16 + tid];
    if (tid >= 12 && tid < 16) it[tid - 12] = intr[bn * 6 + (tid - 12)];
    __syncthreads();

    float fx = it[0], fy = it[1], cx = it[2], cy = it[3];
    float uu = ((float)w - cx) / fx;
    float vv = ((float)h - cy) / fy;
    float dx = p[0] * uu + p[1] * vv + p[2];
    float dy = p[4] * uu + p[5] * vv + p[6];
    float dz = p[8] * uu + p[9] * vv + p[10];
    float inv = rsqrtf(dx * dx + dy * dy + dz * dz);
    size_t o = (size_t)(bn * HW_ + hw) * 3;
    dout[o + 0] = dx * inv;
    dout[o + 1] = dy * inv;
    dout[o + 2] = dz * inv;
}

// ---------------- Kernel 2: scatter-sum ----------------
// sums[b,v,c] += feat[b,n,c,h,w] for hit pixels; cnts[b,v] += 1
__global__ __launch_bounds__(256) void scatter_kernel(
    const float* __restrict__ feat,
    const int* __restrict__ vox_ids,
    const int* __restrict__ hit,
    float* __restrict__ sums,
    unsigned* __restrict__ cnts)
{
    const int PPT = 2;
    const int blocksPerBN = HW_ / (256 * PPT);  // 96
    int tid = threadIdx.x;
    int bn = blockIdx.x / blocksPerBN;
    int b = bn >> 3;
    int hw0 = (blockIdx.x % blocksPerBN) * (256 * PPT) + tid * PPT;
    int r0 = (bn & 7) * HW_ + hw0;

    int2 vid = *(const int2*)(vox_ids + (size_t)b * R_ + r0);
    int2 ht  = *(const int2*)(hit + (size_t)b * R_ + r0);
    if (!(ht.x | ht.y)) return;

    unsigned* cb = cnts + (size_t)b * V_;
    if (ht.x) atomicAdd(&cb[vid.x], 1u);
    if (ht.y) atomicAdd(&cb[vid.y], 1u);

    float* sb = sums + (size_t)b * (size_t)V_ * C_;
    float* s0 = sb + (size_t)vid.x * C_;
    float* s1 = sb + (size_t)vid.y * C_;
    const float* fb = feat + (size_t)bn * C_ * HW_ + hw0;

    #pragma unroll 8
    for (int c = 0; c < C_; ++c) {
        float2 rw = *(const float2*)(fb + (size_t)c * HW_);
        if (ht.x) unsafeAtomicAdd(s0 + c, rw.x);
        if (ht.y) unsafeAtomicAdd(s1 + c, rw.y);
    }
}

// ---------------- Kernel 3: mean + concat(conf) + GEMM + bias ----------------
// out[bv, o] = sum_{c<64} (sums[bv,c]/max(cnt,1)) * w[c,o] + conf[bv]*w[64,o] + bias[o]
__global__ __launch_bounds__(256) void gemm_kernel(
    const float* __restrict__ sums,
    const unsigned* __restrict__ cnts,
    const float* __restrict__ conf,
    const float* __restrict__ wfc,
    const float* __restrict__ bfc,
    float* __restrict__ outp)
{
    const int VPB = 32;  // voxels per block
    __shared__ float wl[65][128];   // 33.3 KB  weights
    __shared__ float voxT[65][36];  // 9.4 KB   transposed vox tile (row 64 = conf)
    __shared__ float bl[128];
    __shared__ float invc[VPB];
    int tid = threadIdx.x;
    int bv0 = blockIdx.x * VPB;

    for (int i = tid; i < 65 * 128; i += 256)
        wl[i >> 7][i & 127] = wfc[i];
    if (tid < 128) bl[tid] = bfc[tid];
    if (tid < VPB) {
        unsigned cn = cnts[bv0 + tid];
        invc[tid] = 1.0f / (float)(cn > 1u ? cn : 1u);
        voxT[64][tid] = conf[bv0 + tid];
    }
    __syncthreads();

    for (int i = tid; i < VPB * C_; i += 256) {
        int vx = i >> 6, c = i & 63;
        voxT[c][vx] = sums[(size_t)bv0 * C_ + i] * invc[vx];
    }
    __syncthreads();

    int oc = tid & 31;   // output quad: o = oc*4 .. oc*4+3
    int vr = tid >> 5;   // voxel quad:  v = vr*4 .. vr*4+3
    float acc[4][4];
    float4 bq = *(float4*)&bl[oc * 4];
    #pragma unroll
    for (int i = 0; i < 4; ++i) {
        acc[i][0] = bq.x; acc[i][1] = bq.y; acc[i][2] = bq.z; acc[i][3] = bq.w;
    }

    #pragma unroll
    for (int c = 0; c < 65; ++c) {
        float4 v4 = *(float4*)&voxT[c][vr * 4];
        float4 w4 = *(float4*)&wl[c][oc * 4];
        acc[0][0] += v4.x * w4.x; acc[0][1] += v4.x * w4.y; acc[0][2] += v4.x * w4.z; acc[0][3] += v4.x * w4.w;
        acc[1][0] += v4.y * w4.x; acc[1][1] += v4.y * w4.y; acc[1][2] += v4.y * w4.z; acc[1][3] += v4.y * w4.w;
        acc[2][0] += v4.z * w4.x; acc[2][1] += v4.z * w4.y; acc[2][2] += v4.z * w4.z; acc[2][3] += v4.z * w4.w;
        acc[3][0] += v4.w * w4.x; acc[3][1] += v4.w * w4.y; acc[3][2] += v4.w * w4.z; acc[3][3] += v4.w * w4.w;
    }

    #pragma unroll
    for (int i = 0; i < 4; ++i) {
        size_t bv = (size_t)(bv0 + vr * 4 + i);
        float4 st;
        st.x = acc[i][0]; st.y = acc[i][1]; st.z = acc[i][2]; st.w = acc[i][3];
        *(float4*)&outp[bv * OUT_ + oc * 4] = st;
    }
}

extern "C" void kernel_launch(void* const* d_in, const int* in_sizes, int n_in,
                              void* d_out, int out_size, void* d_ws, size_t ws_size,
                              hipStream_t stream) {
    const float* pose = (const float*)d_in[0];
    const float* intr = (const float*)d_in[1];
    const float* feat = (const float*)d_in[2];
    // d_in[3] = depths (unused by reference)
    const float* conf = (const float*)d_in[4];
    const int* vox_ids = (const int*)d_in[5];
    const int* hit = (const int*)d_in[6];
    const float* wfc = (const float*)d_in[7];
    const float* bfc = (const float*)d_in[8];

    float* out = (float*)d_out;
    float* dray = out + (size_t)B_ * V_ * OUT_;  // d follows out

    float* sums = (float*)d_ws;
    size_t sums_bytes = (size_t)B_ * V_ * C_ * sizeof(float);   // 102.4 MB
    unsigned* cnts = (unsigned*)((char*)d_ws + sums_bytes);
    size_t cnts_bytes = (size_t)B_ * V_ * sizeof(unsigned);     // 1.6 MB

    hipMemsetAsync(d_ws, 0, sums_bytes + cnts_bytes, stream);

    ray_kernel<<<(B_ * N_ * HW_) / 256, 256, 0, stream>>>(pose, intr, dray);
    scatter_kernel<<<(B_ * N_ * HW_) / (256 * 2), 256, 0, stream>>>(feat, vox_ids, hit, sums, cnts);
    gemm_kernel<<<(B_ * V_) / 32, 256, 0, stream>>>(sums, cnts, conf, wfc, bfc, out);
}